// Round 3
// baseline (230.731 us; speedup 1.0000x reference)
//
#include <hip/hip_runtime.h>
#include <stdint.h>

#define MARGIN 0.3f

typedef __bf16 bf16x8_t __attribute__((ext_vector_type(8)));
typedef float f32x4_t __attribute__((ext_vector_type(4)));

static constexpr int NB = 4096;   // batch
static constexpr int ND = 1024;   // feature dim
static constexpr int NKT = ND / 64;  // 16 K-tiles of BK=64
static constexpr int NIT = NKT / 2;  // 8 double-tile iterations
static constexpr int GRID = 256;     // (4096/256)^2

// RNE float->bf16
__device__ __forceinline__ unsigned short f2bf(float x) {
  union { float f; unsigned u; } v; v.f = x;
  unsigned r = v.u + 0x7FFFu + ((v.u >> 16) & 1u);
  return (unsigned short)(r >> 16);
}

__device__ __forceinline__ void gload_lds16(const void* g, void* l) {
  __builtin_amdgcn_global_load_lds(
      reinterpret_cast<const __attribute__((address_space(1))) uint32_t*>(
          reinterpret_cast<uintptr_t>(g)),
      reinterpret_cast<__attribute__((address_space(3))) uint32_t*>(
          reinterpret_cast<uintptr_t>(l)),
      16, 0, 0);
}

// ---- Kernel 1: fused row-normalize (fp32 stats, bf16 out) + stat init ----
__global__ __launch_bounds__(256) void norm_kernel(
    const float* __restrict__ za, const float* __restrict__ zp,
    __bf16* __restrict__ Ah, __bf16* __restrict__ Ph,
    float* __restrict__ pos, float* __restrict__ ssum,
    int* __restrict__ scnt, unsigned* __restrict__ smin,
    int* __restrict__ done) {
  const int b = blockIdx.x;
  const int t = threadIdx.x;
  const float4 av = reinterpret_cast<const float4*>(za + (size_t)b * ND)[t];
  const float4 pv = reinterpret_cast<const float4*>(zp + (size_t)b * ND)[t];
  float sa = av.x * av.x + av.y * av.y + av.z * av.z + av.w * av.w;
  float sp = pv.x * pv.x + pv.y * pv.y + pv.z * pv.z + pv.w * pv.w;
  float dp = av.x * pv.x + av.y * pv.y + av.z * pv.z + av.w * pv.w;
#pragma unroll
  for (int off = 1; off < 64; off <<= 1) {
    sa += __shfl_xor(sa, off);
    sp += __shfl_xor(sp, off);
    dp += __shfl_xor(dp, off);
  }
  __shared__ float red[3][4];
  const int wid = t >> 6, lane = t & 63;
  if (lane == 0) { red[0][wid] = sa; red[1][wid] = sp; red[2][wid] = dp; }
  __syncthreads();
  sa = red[0][0] + red[0][1] + red[0][2] + red[0][3];
  sp = red[1][0] + red[1][1] + red[1][2] + red[1][3];
  dp = red[2][0] + red[2][1] + red[2][2] + red[2][3];
  const float rsa = rsqrtf(sa), rsp = rsqrtf(sp);
  if (t == 0) {
    pos[b] = 1.0f - dp * rsa * rsp;
    ssum[b] = 0.0f;
    scnt[b] = 0;
    smin[b] = 0x7F800000u;  // +inf bits
    if (b == 0) *done = 0;
  }
  ushort4 oa, op;
  oa.x = f2bf(av.x * rsa); oa.y = f2bf(av.y * rsa);
  oa.z = f2bf(av.z * rsa); oa.w = f2bf(av.w * rsa);
  op.x = f2bf(pv.x * rsp); op.y = f2bf(pv.y * rsp);
  op.z = f2bf(pv.z * rsp); op.w = f2bf(pv.w * rsp);
  reinterpret_cast<ushort4*>(reinterpret_cast<unsigned short*>(Ah) + (size_t)b * ND)[t] = oa;
  reinterpret_cast<ushort4*>(reinterpret_cast<unsigned short*>(Ph) + (size_t)b * ND)[t] = op;
}

// ---- Kernel 2: 256x256 software-pipelined 8-region GEMM + stats + finalize
// LDS planes: A b0 @0, A b1 @32768, B b0 @65536, B b1 @98304 (each 256x128B).
// A-frags read 2 regions ahead (aqX/aqY ping-pong); B-frags read in-region;
// one half-tile stage per region; vmcnt(4) at regions 1,3,5,7.

#define BAR   __builtin_amdgcn_s_barrier()
#define SB0   __builtin_amdgcn_sched_barrier(0)
#define VM4S  do { asm volatile("s_waitcnt vmcnt(4)" ::: "memory"); SB0; } while (0)
#define VM0S  do { asm volatile("s_waitcnt vmcnt(0)" ::: "memory"); SB0; } while (0)
#define PRIO1 __builtin_amdgcn_s_setprio(1)
#define PRIO0 __builtin_amdgcn_s_setprio(0)

#define STAGE_A(buf, half, kt) do { \
    const char* _g = (const char*)Ah + (size_t)(row0 + (half)*128 + srow) * 2048 + (size_t)(kt)*128 + scolb; \
    char* _l = smem + (buf)*32768 + (half)*16384 + w*1024; \
    gload_lds16(_g, _l); \
    gload_lds16(_g + 64*2048, _l + 8192); \
  } while (0)

#define STAGE_B(buf, half, kt) do { \
    const char* _g = (const char*)Ph + (size_t)(col0 + (half)*128 + srow) * 2048 + (size_t)(kt)*128 + scolb; \
    char* _l = smem + 65536 + (buf)*32768 + (half)*16384 + w*1024; \
    gload_lds16(_g, _l); \
    gload_lds16(_g + 64*2048, _l + 8192); \
  } while (0)

#define LD_An(buf, mh, bank) do { _Pragma("unroll") \
    for (int mm = 0; mm < 4; ++mm) { \
      const char* _p = smem + (buf)*32768 + (wr*128 + (mh)*64 + mm*16 + c) * 128; \
      bank[mm][0] = *(const bf16x8_t*)(_p + cswz0); \
      bank[mm][1] = *(const bf16x8_t*)(_p + cswz1); \
    } } while (0)

#define LD_Bn(buf, nh) do { _Pragma("unroll") \
    for (int nn = 0; nn < 2; ++nn) { \
      const char* _p = smem + 65536 + (buf)*32768 + (wc*64 + (nh)*32 + nn*16 + c) * 128; \
      bq[nn][0] = *(const bf16x8_t*)(_p + cswz0); \
      bq[nn][1] = *(const bf16x8_t*)(_p + cswz1); \
    } } while (0)

#define MFMA_Q(mh, nh, ab) do { _Pragma("unroll") \
    for (int kk = 0; kk < 2; ++kk) { _Pragma("unroll") \
      for (int mm = 0; mm < 4; ++mm) { _Pragma("unroll") \
        for (int nn = 0; nn < 2; ++nn) \
          acc[(mh)*4+mm][(nh)*2+nn] = __builtin_amdgcn_mfma_f32_16x16x32_bf16( \
              ab[mm][kk], bq[nn][kk], acc[(mh)*4+mm][(nh)*2+nn], 0, 0, 0); \
      } } } while (0)

__global__ __launch_bounds__(512, 2) void gemm8_kernel(
    const __bf16* __restrict__ Ah, const __bf16* __restrict__ Ph,
    const float* __restrict__ pos, float* __restrict__ ssum,
    int* __restrict__ scnt, unsigned* __restrict__ smin,
    int* __restrict__ done, float* __restrict__ out) {
  extern __shared__ char smem[];
  const int t = threadIdx.x;
  const int lane = t & 63;
  const int w = t >> 6;
  const int wr = w >> 2, wc = w & 3;     // 2x4 wave grid; wave tile 128x64
  const int c = lane & 15, g = lane >> 4;

  // XCD-aware bijective swizzle (256 blocks, 8 XCDs)
  const int wg = blockIdx.x;
  const int swzid = (wg & 7) * 32 + (wg >> 3);
  const int by = swzid >> 4, bx = swzid & 15;
  const int row0 = by * 256, col0 = bx * 256;

  // staging map (linear LDS dest + inverse-swizzled global source, rule 21)
  const int srow = w * 8 + (lane >> 3);
  const int scolb = ((lane & 7) << 4) ^ (((lane >> 3) & 7) << 4);
  const int cswz0 = (g * 16) ^ ((c & 7) << 4);
  const int cswz1 = (64 + g * 16) ^ ((c & 7) << 4);

  f32x4_t acc[8][4] = {};
  bf16x8_t aqX[4][2], aqY[4][2], bq[2][2];

  // Prologue = virtual iter -1 regions r3..r8: stage A(b0,t0), B(b0,t0), A(b1,t1)
  STAGE_A(0, 0, 0); STAGE_A(0, 1, 0);
  STAGE_B(0, 0, 0); STAGE_B(0, 1, 0);
  STAGE_A(1, 0, 1); STAGE_A(1, 1, 1);
  VM4S;                       // drain A(b0),B(b0); leave A(b1) halves in flight
  BAR;
  LD_An(0, 0, aqX);           // A0(t0) for regions 1,2

  for (int i = 0; i < NIT - 1; ++i) {
    const int o = 2 * i + 1;
    // r1: Q00(t2i)  [stage B(b1) t(2i+1) h0]
    VM4S; LD_Bn(0, 0); LD_An(0, 1, aqY); STAGE_B(1, 0, o);
    SB0; BAR; PRIO1; MFMA_Q(0, 0, aqX); PRIO0; BAR;
    // r2: Q01(t2i)  [stage B(b1) h1]
    LD_Bn(0, 1); STAGE_B(1, 1, o);
    SB0; BAR; PRIO1; MFMA_Q(0, 1, aqX); PRIO0; BAR;
    // r3: Q10(t2i)  [stage A(b0) t(2i+2) h0]
    VM4S; LD_Bn(0, 0); LD_An(1, 0, aqX); STAGE_A(0, 0, o + 1);
    SB0; BAR; PRIO1; MFMA_Q(1, 0, aqY); PRIO0; BAR;
    // r4: Q11(t2i)  [stage A(b0) h1]
    LD_Bn(0, 1); STAGE_A(0, 1, o + 1);
    SB0; BAR; PRIO1; MFMA_Q(1, 1, aqY); PRIO0; BAR;
    // r5: Q00(t2i+1) [stage B(b0) t(2i+2) h0]
    VM4S; LD_Bn(1, 0); LD_An(1, 1, aqY); STAGE_B(0, 0, o + 1);
    SB0; BAR; PRIO1; MFMA_Q(0, 0, aqX); PRIO0; BAR;
    // r6: Q01(t2i+1) [stage B(b0) h1]
    LD_Bn(1, 1); STAGE_B(0, 1, o + 1);
    SB0; BAR; PRIO1; MFMA_Q(0, 1, aqX); PRIO0; BAR;
    // r7: Q10(t2i+1) [stage A(b1) t(2i+3) h0]
    VM4S; LD_Bn(1, 0); LD_An(0, 0, aqX); STAGE_A(1, 0, o + 2);
    SB0; BAR; PRIO1; MFMA_Q(1, 0, aqY); PRIO0; BAR;
    // r8: Q11(t2i+1) [stage A(b1) h1]
    LD_Bn(1, 1); STAGE_A(1, 1, o + 2);
    SB0; BAR; PRIO1; MFMA_Q(1, 1, aqY); PRIO0; BAR;
  }

  // Peeled last iteration (tiles 14,15): only B(b1,t15) stages remain
  {
    VM4S; LD_Bn(0, 0); LD_An(0, 1, aqY); STAGE_B(1, 0, 15);
    SB0; BAR; PRIO1; MFMA_Q(0, 0, aqX); PRIO0; BAR;
    LD_Bn(0, 1); STAGE_B(1, 1, 15);
    SB0; BAR; PRIO1; MFMA_Q(0, 1, aqX); PRIO0; BAR;
    VM4S; LD_Bn(0, 0); LD_An(1, 0, aqX);
    SB0; BAR; PRIO1; MFMA_Q(1, 0, aqY); PRIO0; BAR;
    LD_Bn(0, 1);
    BAR; PRIO1; MFMA_Q(1, 1, aqY); PRIO0; BAR;
    VM0S; LD_Bn(1, 0); LD_An(1, 1, aqY);   // B(b1,t15) staged r1,r2 only -> drain all
    SB0; BAR; PRIO1; MFMA_Q(0, 0, aqX); PRIO0; BAR;
    LD_Bn(1, 1);
    BAR; PRIO1; MFMA_Q(0, 1, aqX); PRIO0; BAR;
    LD_Bn(1, 0);
    PRIO1; MFMA_Q(1, 0, aqY); PRIO0;
    LD_Bn(1, 1);
    PRIO1; MFMA_Q(1, 1, aqY); PRIO0;
  }

  // Epilogue: per-row {sum,cnt,min} over this block's 256-col slice.
#pragma unroll
  for (int m = 0; m < 8; ++m) {
#pragma unroll
    for (int r = 0; r < 4; ++r) {
      const int grow = row0 + wr * 128 + m * 16 + g * 4 + r;
      const float pd = pos[grow];
      float s = 0.0f;
      int ct = 0;
      float mn = 3.0e38f;
#pragma unroll
      for (int n = 0; n < 4; ++n) {
        const int gcol = col0 + wc * 64 + n * 16 + c;
        const float v = 1.0f - acc[m][n][r];
        if (gcol != grow) {
          mn = fminf(mn, v);
          if (v > pd && v < pd + MARGIN) { s += v; ct += 1; }
        }
      }
#pragma unroll
      for (int off = 1; off < 16; off <<= 1) {
        s += __shfl_xor(s, off);
        ct += __shfl_xor(ct, off);
        mn = fminf(mn, __shfl_xor(mn, off));
      }
      if (c == 0) {
        atomicAdd(&ssum[grow], s);
        atomicAdd(&scnt[grow], ct);
        atomicMin(&smin[grow], __float_as_uint(mn));
      }
    }
  }

  // ---- fused finalize: last block to finish combines stats -> loss ----
  __shared__ int lastBlk;
  __syncthreads();               // drains this block's atomics (vmcnt)
  if (t == 0) {
    __threadfence();             // device-scope release
    lastBlk = (atomicAdd(done, 1) == GRID - 1) ? 1 : 0;
  }
  __syncthreads();
  if (!lastBlk) return;

  float accv = 0.0f;
#pragma unroll
  for (int it = 0; it < NB / 512; ++it) {
    const int rr = t + it * 512;
    const float pd = __hip_atomic_load(&pos[rr], __ATOMIC_RELAXED, __HIP_MEMORY_SCOPE_AGENT);
    const float sm = __hip_atomic_load(&ssum[rr], __ATOMIC_RELAXED, __HIP_MEMORY_SCOPE_AGENT);
    const int ct = __hip_atomic_load(&scnt[rr], __ATOMIC_RELAXED, __HIP_MEMORY_SCOPE_AGENT);
    const unsigned mnb = __hip_atomic_load(&smin[rr], __ATOMIC_RELAXED, __HIP_MEMORY_SCOPE_AGENT);
    const float neg = ct > 0 ? sm / (float)ct : __uint_as_float(mnb);
    accv += fmaxf(pd - neg + MARGIN, 0.0f);
  }
#pragma unroll
  for (int off = 1; off < 64; off <<= 1) accv += __shfl_xor(accv, off);
  __shared__ float fred[8];
  if (lane == 0) fred[w] = accv;
  __syncthreads();
  if (t == 0) {
    float tot = 0.0f;
#pragma unroll
    for (int i = 0; i < 8; ++i) tot += fred[i];
    out[0] = tot * (1.0f / NB);
  }
}

extern "C" void kernel_launch(void* const* d_in, const int* in_sizes, int n_in,
                              void* d_out, int out_size, void* d_ws, size_t ws_size,
                              hipStream_t stream) {
  const float* za = (const float*)d_in[0];
  const float* zp = (const float*)d_in[1];
  float* out = (float*)d_out;
  char* ws = (char*)d_ws;
  __bf16* Ah = (__bf16*)(ws);                                   // 8 MB
  __bf16* Ph = (__bf16*)(ws + (size_t)NB * ND * 2);             // 8 MB
  float* pos = (float*)(ws + (size_t)NB * ND * 4);              // 16 KB
  float* ssum = pos + NB;                                       // 16 KB
  int* scnt = (int*)(ssum + NB);                                // 16 KB
  unsigned* smin = (unsigned*)(scnt + NB);                      // 16 KB
  int* done = (int*)(smin + NB);                                // 4 B

  (void)hipFuncSetAttribute((const void*)gemm8_kernel,
                            hipFuncAttributeMaxDynamicSharedMemorySize, 131072);

  norm_kernel<<<NB, 256, 0, stream>>>(za, zp, Ah, Ph, pos, ssum, scnt, smin, done);
  gemm8_kernel<<<GRID, 512, 131072, stream>>>(Ah, Ph, pos, ssum, scnt, smin, done, out);
}

// Round 4
// 210.647 us; speedup vs baseline: 1.0953x; 1.0953x over previous
//
#include <hip/hip_runtime.h>
#include <stdint.h>

#define MARGIN 0.3f

typedef __bf16 bf16x8_t __attribute__((ext_vector_type(8)));
typedef float f32x4_t __attribute__((ext_vector_type(4)));

static constexpr int NB = 4096;   // batch
static constexpr int ND = 1024;   // feature dim
static constexpr int NKT = ND / 64;  // 16 K-tiles of BK=64
static constexpr int NIT = NKT / 2;  // 8 double-tile iterations
static constexpr int GRID = 256;     // (4096/256)^2

// RNE float->bf16
__device__ __forceinline__ unsigned short f2bf(float x) {
  union { float f; unsigned u; } v; v.f = x;
  unsigned r = v.u + 0x7FFFu + ((v.u >> 16) & 1u);
  return (unsigned short)(r >> 16);
}

__device__ __forceinline__ void gload_lds16(const void* g, void* l) {
  __builtin_amdgcn_global_load_lds(
      reinterpret_cast<const __attribute__((address_space(1))) uint32_t*>(
          reinterpret_cast<uintptr_t>(g)),
      reinterpret_cast<__attribute__((address_space(3))) uint32_t*>(
          reinterpret_cast<uintptr_t>(l)),
      16, 0, 0);
}

// ---- Kernel 1: fused row-normalize (fp32 stats, bf16 out) + stat init ----
__global__ __launch_bounds__(256) void norm_kernel(
    const float* __restrict__ za, const float* __restrict__ zp,
    __bf16* __restrict__ Ah, __bf16* __restrict__ Ph,
    float* __restrict__ pos, float* __restrict__ ssum,
    int* __restrict__ scnt, unsigned* __restrict__ smin,
    int* __restrict__ done) {
  const int b = blockIdx.x;
  const int t = threadIdx.x;
  const float4 av = reinterpret_cast<const float4*>(za + (size_t)b * ND)[t];
  const float4 pv = reinterpret_cast<const float4*>(zp + (size_t)b * ND)[t];
  float sa = av.x * av.x + av.y * av.y + av.z * av.z + av.w * av.w;
  float sp = pv.x * pv.x + pv.y * pv.y + pv.z * pv.z + pv.w * pv.w;
  float dp = av.x * pv.x + av.y * pv.y + av.z * pv.z + av.w * pv.w;
#pragma unroll
  for (int off = 1; off < 64; off <<= 1) {
    sa += __shfl_xor(sa, off);
    sp += __shfl_xor(sp, off);
    dp += __shfl_xor(dp, off);
  }
  __shared__ float red[3][4];
  const int wid = t >> 6, lane = t & 63;
  if (lane == 0) { red[0][wid] = sa; red[1][wid] = sp; red[2][wid] = dp; }
  __syncthreads();
  sa = red[0][0] + red[0][1] + red[0][2] + red[0][3];
  sp = red[1][0] + red[1][1] + red[1][2] + red[1][3];
  dp = red[2][0] + red[2][1] + red[2][2] + red[2][3];
  const float rsa = rsqrtf(sa), rsp = rsqrtf(sp);
  if (t == 0) {
    pos[b] = 1.0f - dp * rsa * rsp;
    ssum[b] = 0.0f;
    scnt[b] = 0;
    smin[b] = 0x7F800000u;  // +inf bits
    if (b == 0) *done = 0;
  }
  ushort4 oa, op;
  oa.x = f2bf(av.x * rsa); oa.y = f2bf(av.y * rsa);
  oa.z = f2bf(av.z * rsa); oa.w = f2bf(av.w * rsa);
  op.x = f2bf(pv.x * rsp); op.y = f2bf(pv.y * rsp);
  op.z = f2bf(pv.z * rsp); op.w = f2bf(pv.w * rsp);
  reinterpret_cast<ushort4*>(reinterpret_cast<unsigned short*>(Ah) + (size_t)b * ND)[t] = oa;
  reinterpret_cast<ushort4*>(reinterpret_cast<unsigned short*>(Ph) + (size_t)b * ND)[t] = op;
}

// ---- Kernel 2: 256x256 8-phase GEMM fused with per-row semi-hard stats ---
// BM=BN=256, BK=64, 8 waves (2Mx4N), 512 thr, 128 KiB LDS double-buffer.
// LDS planes: A b0 @0, A b1 @32768, B b0 @65536, B b1 @98304.
// Plane layout: [256 rows][64 bf16] = 128 B/row; XOR-swizzle byte^=((row&7)<<4)
// realized as linear LDS dest + inverse-swizzled GLOBAL source (rule 21).
// No manual lgkmcnt: compiler emits counted per-use waits (m97 r109).

#define BAR   __builtin_amdgcn_s_barrier()
#define VM4   asm volatile("s_waitcnt vmcnt(4)" ::: "memory")
#define VM0   asm volatile("s_waitcnt vmcnt(0)" ::: "memory")
#define PRIO1 __builtin_amdgcn_s_setprio(1)
#define PRIO0 __builtin_amdgcn_s_setprio(0)

#define STAGE_A(buf, half, kt) do { \
    const char* _g = (const char*)Ah + (size_t)(row0 + (half)*128 + srow) * 2048 + (size_t)(kt)*128 + scolb; \
    char* _l = smem + (buf)*32768 + (half)*16384 + w*1024; \
    gload_lds16(_g, _l); \
    gload_lds16(_g + 64*2048, _l + 8192); \
  } while (0)

#define STAGE_B(buf, half, kt) do { \
    const char* _g = (const char*)Ph + (size_t)(col0 + (half)*128 + srow) * 2048 + (size_t)(kt)*128 + scolb; \
    char* _l = smem + 65536 + (buf)*32768 + (half)*16384 + w*1024; \
    gload_lds16(_g, _l); \
    gload_lds16(_g + 64*2048, _l + 8192); \
  } while (0)

#define LD_A(buf, mh, bank) do { _Pragma("unroll") \
    for (int mm = 0; mm < 4; ++mm) { \
      const char* _p = smem + (buf)*32768 + (wr*128 + (mh)*64 + mm*16 + c) * 128; \
      bank[mm][0] = *(const bf16x8_t*)(_p + cswz0); \
      bank[mm][1] = *(const bf16x8_t*)(_p + cswz1); \
    } } while (0)

#define LD_B(buf, nh, dst) do { _Pragma("unroll") \
    for (int nn = 0; nn < 2; ++nn) { \
      const char* _p = smem + 65536 + (buf)*32768 + (wc*64 + (nh)*32 + nn*16 + c) * 128; \
      dst[nn][0] = *(const bf16x8_t*)(_p + cswz0); \
      dst[nn][1] = *(const bf16x8_t*)(_p + cswz1); \
    } } while (0)

#define MFMA_Q(mh, bq, nh, ab) do { _Pragma("unroll") \
    for (int kk = 0; kk < 2; ++kk) { _Pragma("unroll") \
      for (int mm = 0; mm < 4; ++mm) { _Pragma("unroll") \
        for (int nn = 0; nn < 2; ++nn) \
          acc[(mh)*4+mm][(nh)*2+nn] = __builtin_amdgcn_mfma_f32_16x16x32_bf16( \
              ab[mm][kk], bq[nn][kk], acc[(mh)*4+mm][(nh)*2+nn], 0, 0, 0); \
      } } } while (0)

__global__ __launch_bounds__(512, 2) void gemm8_kernel(
    const __bf16* __restrict__ Ah, const __bf16* __restrict__ Ph,
    const float* __restrict__ pos, float* __restrict__ ssum,
    int* __restrict__ scnt, unsigned* __restrict__ smin,
    int* __restrict__ done, float* __restrict__ out) {
  extern __shared__ char smem[];
  const int t = threadIdx.x;
  const int lane = t & 63;
  const int w = t >> 6;
  const int wr = w >> 2, wc = w & 3;     // 2x4 wave grid; wave tile 128x64
  const int c = lane & 15, g = lane >> 4;

  // XCD-aware bijective swizzle (256 blocks, 8 XCDs)
  const int wg = blockIdx.x;
  const int swzid = (wg & 7) * 32 + (wg >> 3);
  const int by = swzid >> 4, bx = swzid & 15;
  const int row0 = by * 256, col0 = bx * 256;

  // staging map (linear LDS dest + inverse-swizzled global source, rule 21)
  const int srow = w * 8 + (lane >> 3);
  const int scolb = ((lane & 7) << 4) ^ (((lane >> 3) & 7) << 4);
  const int cswz0 = (g * 16) ^ ((c & 7) << 4);
  const int cswz1 = (64 + g * 16) ^ ((c & 7) << 4);

  f32x4_t acc[8][4] = {};
  bf16x8_t aqA[4][2], aqB[4][2], bq0[2][2], bq1[2][2];

  // Prologue: tile0 -> buf0 (B then A), tile1 B -> buf1.
  // vmcnt(4) leaves only the 2 buf1.B half-tiles in flight; buf0 landed.
  STAGE_B(0, 0, 0); STAGE_B(0, 1, 0);
  STAGE_A(0, 0, 0); STAGE_A(0, 1, 0);
  STAGE_B(1, 0, 1); STAGE_B(1, 1, 1);
  VM4; BAR;

  for (int i = 0; i < NIT; ++i) {
    const int o = 2 * i + 1;
    const bool st = (i < NIT - 1);
    // ph1: read buf0 A(mh0) + B(nh0) + B(nh1); stage buf1.A h0 (tile 2i+1)
    LD_A(0, 0, aqA); LD_B(0, 0, bq0); LD_B(0, 1, bq1);
    STAGE_A(1, 0, o);
    BAR; PRIO1; MFMA_Q(0, bq0, 0, aqA); PRIO0; BAR;
    // ph2: read buf0 A(mh1); stage buf1.A h1
    LD_A(0, 1, aqB);
    STAGE_A(1, 1, o);
    BAR; PRIO1; MFMA_Q(0, bq1, 1, aqA); PRIO0; BAR;
    // ph3: (no reads); stage buf0.B h0 (tile 2i+2; buf0.B reads completed by ph2)
    if (st) STAGE_B(0, 0, o + 1);
    BAR; PRIO1; MFMA_Q(1, bq0, 0, aqB); PRIO0; BAR;
    // ph4: stage buf0.B h1; vmcnt ensures buf1 (tile 2i+1) fully landed
    if (st) STAGE_B(0, 1, o + 1);
    PRIO1; MFMA_Q(1, bq1, 1, aqB); PRIO0;
    if (st) { VM4; } else { VM0; }
    BAR;
    // ph5: read buf1 A(mh0) + B(nh0) + B(nh1); stage buf0.A h0 (tile 2i+2)
    LD_A(1, 0, aqA); LD_B(1, 0, bq0); LD_B(1, 1, bq1);
    if (st) STAGE_A(0, 0, o + 1);
    BAR; PRIO1; MFMA_Q(0, bq0, 0, aqA); PRIO0; BAR;
    // ph6: read buf1 A(mh1); stage buf0.A h1
    LD_A(1, 1, aqB);
    if (st) STAGE_A(0, 1, o + 1);
    BAR; PRIO1; MFMA_Q(0, bq1, 1, aqA); PRIO0; BAR;
    // ph7: (no reads); stage buf1.B h0 (tile 2i+3; buf1.B reads completed by ph6)
    if (st) STAGE_B(1, 0, o + 2);
    BAR; PRIO1; MFMA_Q(1, bq0, 0, aqB); PRIO0; BAR;
    // ph8: stage buf1.B h1; vmcnt ensures buf0 (tile 2i+2) fully landed
    if (st) STAGE_B(1, 1, o + 2);
    PRIO1; MFMA_Q(1, bq1, 1, aqB); PRIO0;
    if (st) { VM4; } else { VM0; }
    BAR;
  }

  // Epilogue: per-row {sum,cnt,min} over this block's 256-col slice.
  // C frag layout: col = c, row = g*4 + r within each 16x16 tile.
#pragma unroll
  for (int m = 0; m < 8; ++m) {
#pragma unroll
    for (int r = 0; r < 4; ++r) {
      const int grow = row0 + wr * 128 + m * 16 + g * 4 + r;
      const float pd = pos[grow];
      float s = 0.0f;
      int ct = 0;
      float mn = 3.0e38f;
#pragma unroll
      for (int n = 0; n < 4; ++n) {
        const int gcol = col0 + wc * 64 + n * 16 + c;
        const float v = 1.0f - acc[m][n][r];
        if (gcol != grow) {
          mn = fminf(mn, v);
          if (v > pd && v < pd + MARGIN) { s += v; ct += 1; }
        }
      }
#pragma unroll
      for (int off = 1; off < 16; off <<= 1) {
        s += __shfl_xor(s, off);
        ct += __shfl_xor(ct, off);
        mn = fminf(mn, __shfl_xor(mn, off));
      }
      if (c == 0) {
        atomicAdd(&ssum[grow], s);
        atomicAdd(&scnt[grow], ct);
        atomicMin(&smin[grow], __float_as_uint(mn));
      }
    }
  }

  // ---- fused finalize: last block to finish combines stats -> loss ----
  __shared__ int lastBlk;
  __syncthreads();               // block's atomics issued
  if (t == 0) {
    __threadfence();             // release prior stats writes (device scope)
    lastBlk = (atomicAdd(done, 1) == GRID - 1) ? 1 : 0;
    if (lastBlk) __threadfence();  // acquire other blocks' stats
  }
  __syncthreads();
  if (!lastBlk) return;

  float accv = 0.0f;
#pragma unroll
  for (int it = 0; it < NB / 512; ++it) {
    const int rr = t + it * 512;
    const float pd = __hip_atomic_load(&pos[rr], __ATOMIC_RELAXED, __HIP_MEMORY_SCOPE_AGENT);
    const float sm = __hip_atomic_load(&ssum[rr], __ATOMIC_RELAXED, __HIP_MEMORY_SCOPE_AGENT);
    const int ct = __hip_atomic_load(&scnt[rr], __ATOMIC_RELAXED, __HIP_MEMORY_SCOPE_AGENT);
    const unsigned mnb = __hip_atomic_load(&smin[rr], __ATOMIC_RELAXED, __HIP_MEMORY_SCOPE_AGENT);
    const float neg = ct > 0 ? sm / (float)ct : __uint_as_float(mnb);
    accv += fmaxf(pd - neg + MARGIN, 0.0f);
  }
#pragma unroll
  for (int off = 1; off < 64; off <<= 1) accv += __shfl_xor(accv, off);
  __shared__ float fred[8];
  if (lane == 0) fred[w] = accv;
  __syncthreads();
  if (t == 0) {
    float tot = 0.0f;
#pragma unroll
    for (int i = 0; i < 8; ++i) tot += fred[i];
    out[0] = tot * (1.0f / NB);
  }
}

extern "C" void kernel_launch(void* const* d_in, const int* in_sizes, int n_in,
                              void* d_out, int out_size, void* d_ws, size_t ws_size,
                              hipStream_t stream) {
  const float* za = (const float*)d_in[0];
  const float* zp = (const float*)d_in[1];
  float* out = (float*)d_out;
  char* ws = (char*)d_ws;
  __bf16* Ah = (__bf16*)(ws);                                   // 8 MB
  __bf16* Ph = (__bf16*)(ws + (size_t)NB * ND * 2);             // 8 MB
  float* pos = (float*)(ws + (size_t)NB * ND * 4);              // 16 KB
  float* ssum = pos + NB;                                       // 16 KB
  int* scnt = (int*)(ssum + NB);                                // 16 KB
  unsigned* smin = (unsigned*)(scnt + NB);                      // 16 KB
  int* done = (int*)(smin + NB);                                // 4 B

  (void)hipFuncSetAttribute((const void*)gemm8_kernel,
                            hipFuncAttributeMaxDynamicSharedMemorySize, 131072);

  norm_kernel<<<NB, 256, 0, stream>>>(za, zp, Ah, Ph, pos, ssum, scnt, smin, done);
  gemm8_kernel<<<GRID, 512, 131072, stream>>>(Ah, Ph, pos, ssum, scnt, smin, done, out);
}

// Round 5
// 203.943 us; speedup vs baseline: 1.1314x; 1.0329x over previous
//
#include <hip/hip_runtime.h>
#include <stdint.h>

#define MARGIN 0.3f

typedef __bf16 bf16x8_t __attribute__((ext_vector_type(8)));
typedef float f32x4_t __attribute__((ext_vector_type(4)));

static constexpr int NB = 4096;   // batch
static constexpr int ND = 1024;   // feature dim
static constexpr int NKT = ND / 64;  // 16 K-tiles of BK=64
static constexpr int NIT = NKT / 2;  // 8 double-tile iterations
static constexpr int GRID = 256;     // (4096/256)^2

// RNE float->bf16
__device__ __forceinline__ unsigned short f2bf(float x) {
  union { float f; unsigned u; } v; v.f = x;
  unsigned r = v.u + 0x7FFFu + ((v.u >> 16) & 1u);
  return (unsigned short)(r >> 16);
}

__device__ __forceinline__ void gload_lds16(const void* g, void* l) {
  __builtin_amdgcn_global_load_lds(
      reinterpret_cast<const __attribute__((address_space(1))) uint32_t*>(
          reinterpret_cast<uintptr_t>(g)),
      reinterpret_cast<__attribute__((address_space(3))) uint32_t*>(
          reinterpret_cast<uintptr_t>(l)),
      16, 0, 0);
}

// ---- Kernel 1: fused row-normalize (fp32 stats, bf16 out) + stat init ----
__global__ __launch_bounds__(256) void norm_kernel(
    const float* __restrict__ za, const float* __restrict__ zp,
    __bf16* __restrict__ Ah, __bf16* __restrict__ Ph,
    float* __restrict__ pos, float* __restrict__ ssum,
    int* __restrict__ scnt, unsigned* __restrict__ smin,
    int* __restrict__ done) {
  const int b = blockIdx.x;
  const int t = threadIdx.x;
  const float4 av = reinterpret_cast<const float4*>(za + (size_t)b * ND)[t];
  const float4 pv = reinterpret_cast<const float4*>(zp + (size_t)b * ND)[t];
  float sa = av.x * av.x + av.y * av.y + av.z * av.z + av.w * av.w;
  float sp = pv.x * pv.x + pv.y * pv.y + pv.z * pv.z + pv.w * pv.w;
  float dp = av.x * pv.x + av.y * pv.y + av.z * pv.z + av.w * pv.w;
#pragma unroll
  for (int off = 1; off < 64; off <<= 1) {
    sa += __shfl_xor(sa, off);
    sp += __shfl_xor(sp, off);
    dp += __shfl_xor(dp, off);
  }
  __shared__ float red[3][4];
  const int wid = t >> 6, lane = t & 63;
  if (lane == 0) { red[0][wid] = sa; red[1][wid] = sp; red[2][wid] = dp; }
  __syncthreads();
  sa = red[0][0] + red[0][1] + red[0][2] + red[0][3];
  sp = red[1][0] + red[1][1] + red[1][2] + red[1][3];
  dp = red[2][0] + red[2][1] + red[2][2] + red[2][3];
  const float rsa = rsqrtf(sa), rsp = rsqrtf(sp);
  if (t == 0) {
    pos[b] = 1.0f - dp * rsa * rsp;
    ssum[b] = 0.0f;
    scnt[b] = 0;
    smin[b] = 0x7F800000u;  // +inf bits
    if (b == 0) *done = 0;
  }
  ushort4 oa, op;
  oa.x = f2bf(av.x * rsa); oa.y = f2bf(av.y * rsa);
  oa.z = f2bf(av.z * rsa); oa.w = f2bf(av.w * rsa);
  op.x = f2bf(pv.x * rsp); op.y = f2bf(pv.y * rsp);
  op.z = f2bf(pv.z * rsp); op.w = f2bf(pv.w * rsp);
  reinterpret_cast<ushort4*>(reinterpret_cast<unsigned short*>(Ah) + (size_t)b * ND)[t] = oa;
  reinterpret_cast<ushort4*>(reinterpret_cast<unsigned short*>(Ph) + (size_t)b * ND)[t] = op;
}

// ---- Kernel 2: 256x256 8-phase GEMM, low-pressure schedule --------------
// 8 waves (2Mx4N), wave tile 128x64. LDS planes: A b0 @0, A b1 @32768,
// B b0 @65536, B b1 @98304; [256 rows][128 B]; XOR-swizzle via pre-swizzled
// global source + swizzled ds_read (rule 21).
// Frags: aq single bank (32 VGPR), bq0/bq1 (32 VGPR). acc 128 (AGPR).
// 2 vmcnt(4) waits/iter (r1, r5); 1 barrier/phase; no manual lgkmcnt.

#define BARM  asm volatile("s_barrier" ::: "memory")
#define VM4   asm volatile("s_waitcnt vmcnt(4)" ::: "memory")
#define VM0   asm volatile("s_waitcnt vmcnt(0)" ::: "memory")
#define PRIO1 __builtin_amdgcn_s_setprio(1)
#define PRIO0 __builtin_amdgcn_s_setprio(0)

#define STAGE_A(buf, half, kt) do { \
    const char* _g = (const char*)Ah + (size_t)(row0 + (half)*128 + srow) * 2048 + (size_t)(kt)*128 + scolb; \
    char* _l = smem + (buf)*32768 + (half)*16384 + w*1024; \
    gload_lds16(_g, _l); \
    gload_lds16(_g + 64*2048, _l + 8192); \
  } while (0)

#define STAGE_B(buf, half, kt) do { \
    const char* _g = (const char*)Ph + (size_t)(col0 + (half)*128 + srow) * 2048 + (size_t)(kt)*128 + scolb; \
    char* _l = smem + 65536 + (buf)*32768 + (half)*16384 + w*1024; \
    gload_lds16(_g, _l); \
    gload_lds16(_g + 64*2048, _l + 8192); \
  } while (0)

#define LD_A(buf, mh) do { _Pragma("unroll") \
    for (int mm = 0; mm < 4; ++mm) { \
      const char* _p = smem + (buf)*32768 + (wr*128 + (mh)*64 + mm*16 + c) * 128; \
      aq[mm][0] = *(const bf16x8_t*)(_p + cswz0); \
      aq[mm][1] = *(const bf16x8_t*)(_p + cswz1); \
    } } while (0)

#define LD_B(buf, nh, dst) do { _Pragma("unroll") \
    for (int nn = 0; nn < 2; ++nn) { \
      const char* _p = smem + 65536 + (buf)*32768 + (wc*64 + (nh)*32 + nn*16 + c) * 128; \
      dst[nn][0] = *(const bf16x8_t*)(_p + cswz0); \
      dst[nn][1] = *(const bf16x8_t*)(_p + cswz1); \
    } } while (0)

#define MFMA_Q(mh, nh, bqx) do { _Pragma("unroll") \
    for (int kk = 0; kk < 2; ++kk) { _Pragma("unroll") \
      for (int mm = 0; mm < 4; ++mm) { _Pragma("unroll") \
        for (int nn = 0; nn < 2; ++nn) \
          acc[(mh)*4+mm][(nh)*2+nn] = __builtin_amdgcn_mfma_f32_16x16x32_bf16( \
              aq[mm][kk], bqx[nn][kk], acc[(mh)*4+mm][(nh)*2+nn], 0, 0, 0); \
      } } } while (0)

__global__ __launch_bounds__(512, 2) void gemm8_kernel(
    const __bf16* __restrict__ Ah, const __bf16* __restrict__ Ph,
    const float* __restrict__ pos, float* __restrict__ ssum,
    int* __restrict__ scnt, unsigned* __restrict__ smin,
    int* __restrict__ done, float* __restrict__ out) {
  extern __shared__ char smem[];
  const int t = threadIdx.x;
  const int lane = t & 63;
  const int w = t >> 6;
  const int wr = w >> 2, wc = w & 3;     // 2x4 wave grid; wave tile 128x64
  const int c = lane & 15, g = lane >> 4;

  // XCD-aware bijective swizzle (256 blocks, 8 XCDs)
  const int wg = blockIdx.x;
  const int swzid = (wg & 7) * 32 + (wg >> 3);
  const int by = swzid >> 4, bx = swzid & 15;
  const int row0 = by * 256, col0 = bx * 256;

  // staging map (linear LDS dest + inverse-swizzled global source)
  const int srow = w * 8 + (lane >> 3);
  const int scolb = ((lane & 7) << 4) ^ (((lane >> 3) & 7) << 4);
  const int cswz0 = (g * 16) ^ ((c & 7) << 4);
  const int cswz1 = (64 + g * 16) ^ ((c & 7) << 4);

  f32x4_t acc[8][4] = {};
  bf16x8_t aq[4][2], bq0[2][2], bq1[2][2];

  // Prologue: buf0 <- tile0 (A,B); buf1 <- A h0 of tile1. (10 loads in flight)
  STAGE_A(0, 0, 0); STAGE_A(0, 1, 0);
  STAGE_B(0, 0, 0); STAGE_B(0, 1, 0);
  STAGE_A(1, 0, 1);

  for (int i = 0; i < NIT; ++i) {
    const int o = 2 * i + 1;
    const bool st = (i < NIT - 1);
    // r1: stage B1h0(t2i+1); vm4 drains tile-2i buf0 planes; reads A0mh0+B0
    STAGE_B(1, 0, o);
    VM4; BARM;
    LD_A(0, 0); LD_B(0, 0, bq0); LD_B(0, 1, bq1);
    PRIO1; MFMA_Q(0, 0, bq0); PRIO0;
    // r2: stage B1h1; MFMA-only
    STAGE_B(1, 1, o);
    BARM;
    PRIO1; MFMA_Q(0, 1, bq1); PRIO0;
    // r3: stage A1h1(t2i+1); read A0mh1
    STAGE_A(1, 1, o);
    BARM;
    LD_A(0, 1);
    PRIO1; MFMA_Q(1, 0, bq0); PRIO0;
    // r4: stage A0'h0(t2i+2); MFMA-only
    if (st) STAGE_A(0, 0, o + 1);
    BARM;
    PRIO1; MFMA_Q(1, 1, bq1); PRIO0;
    // r5: stage A0'h1; vm4 drains tile-2i+1 buf1 planes; reads A1mh0+B1
    if (st) { STAGE_A(0, 1, o + 1); VM4; } else { VM0; }
    BARM;
    LD_A(1, 0); LD_B(1, 0, bq0); LD_B(1, 1, bq1);
    PRIO1; MFMA_Q(0, 0, bq0); PRIO0;
    // r6: stage B0'h0(t2i+2); MFMA-only
    if (st) STAGE_B(0, 0, o + 1);
    BARM;
    PRIO1; MFMA_Q(0, 1, bq1); PRIO0;
    // r7: stage B0'h1; read A1mh1
    if (st) STAGE_B(0, 1, o + 1);
    BARM;
    LD_A(1, 1);
    PRIO1; MFMA_Q(1, 0, bq0); PRIO0;
    // r8: stage A1'h0(t2i+3); MFMA-only
    if (st) STAGE_A(1, 0, o + 2);
    BARM;
    PRIO1; MFMA_Q(1, 1, bq1); PRIO0;
  }

  // Epilogue: per-row {sum,cnt,min} over this block's 256-col slice.
  // C frag layout: col = c, row = g*4 + r within each 16x16 tile.
#pragma unroll
  for (int m = 0; m < 8; ++m) {
#pragma unroll
    for (int r = 0; r < 4; ++r) {
      const int grow = row0 + wr * 128 + m * 16 + g * 4 + r;
      const float pd = pos[grow];
      float s = 0.0f;
      int ct = 0;
      float mn = 3.0e38f;
#pragma unroll
      for (int n = 0; n < 4; ++n) {
        const int gcol = col0 + wc * 64 + n * 16 + c;
        const float v = 1.0f - acc[m][n][r];
        if (gcol != grow) {
          mn = fminf(mn, v);
          if (v > pd && v < pd + MARGIN) { s += v; ct += 1; }
        }
      }
#pragma unroll
      for (int off = 1; off < 16; off <<= 1) {
        s += __shfl_xor(s, off);
        ct += __shfl_xor(ct, off);
        mn = fminf(mn, __shfl_xor(mn, off));
      }
      if (c == 0) {
        atomicAdd(&ssum[grow], s);
        atomicAdd(&scnt[grow], ct);
        atomicMin(&smin[grow], __float_as_uint(mn));
      }
    }
  }

  // ---- fused finalize: last block to finish combines stats -> loss ----
  __shared__ int lastBlk;
  __syncthreads();
  if (t == 0) {
    __threadfence();             // release this block's stats
    lastBlk = (atomicAdd(done, 1) == GRID - 1) ? 1 : 0;
    if (lastBlk) __threadfence();  // acquire other blocks' stats
  }
  __syncthreads();
  if (!lastBlk) return;

  float accv = 0.0f;
#pragma unroll
  for (int it = 0; it < NB / 512; ++it) {
    const int rr = t + it * 512;
    const float pd = __hip_atomic_load(&pos[rr], __ATOMIC_RELAXED, __HIP_MEMORY_SCOPE_AGENT);
    const float sm = __hip_atomic_load(&ssum[rr], __ATOMIC_RELAXED, __HIP_MEMORY_SCOPE_AGENT);
    const int ct = __hip_atomic_load(&scnt[rr], __ATOMIC_RELAXED, __HIP_MEMORY_SCOPE_AGENT);
    const unsigned mnb = __hip_atomic_load(&smin[rr], __ATOMIC_RELAXED, __HIP_MEMORY_SCOPE_AGENT);
    const float neg = ct > 0 ? sm / (float)ct : __uint_as_float(mnb);
    accv += fmaxf(pd - neg + MARGIN, 0.0f);
  }
#pragma unroll
  for (int off = 1; off < 64; off <<= 1) accv += __shfl_xor(accv, off);
  __shared__ float fred[8];
  if (lane == 0) fred[w] = accv;
  __syncthreads();
  if (t == 0) {
    float tot = 0.0f;
#pragma unroll
    for (int i = 0; i < 8; ++i) tot += fred[i];
    out[0] = tot * (1.0f / NB);
  }
}

extern "C" void kernel_launch(void* const* d_in, const int* in_sizes, int n_in,
                              void* d_out, int out_size, void* d_ws, size_t ws_size,
                              hipStream_t stream) {
  const float* za = (const float*)d_in[0];
  const float* zp = (const float*)d_in[1];
  float* out = (float*)d_out;
  char* ws = (char*)d_ws;
  __bf16* Ah = (__bf16*)(ws);                                   // 8 MB
  __bf16* Ph = (__bf16*)(ws + (size_t)NB * ND * 2);             // 8 MB
  float* pos = (float*)(ws + (size_t)NB * ND * 4);              // 16 KB
  float* ssum = pos + NB;                                       // 16 KB
  int* scnt = (int*)(ssum + NB);                                // 16 KB
  unsigned* smin = (unsigned*)(scnt + NB);                      // 16 KB
  int* done = (int*)(smin + NB);                                // 4 B

  (void)hipFuncSetAttribute((const void*)gemm8_kernel,
                            hipFuncAttributeMaxDynamicSharedMemorySize, 131072);

  norm_kernel<<<NB, 256, 0, stream>>>(za, zp, Ah, Ph, pos, ssum, scnt, smin, done);
  gemm8_kernel<<<GRID, 512, 131072, stream>>>(Ah, Ph, pos, ssum, scnt, smin, done, out);
}